// Round 3
// baseline (1151.596 us; speedup 1.0000x reference)
//
#include <hip/hip_runtime.h>
#include <math.h>

// 2-layer LSTM (B=1024,T=512,F=64,H=128) + FC head.
// R8: R7 structure (layer-pipelined producer/consumer, cooperative LDS
// staging, [t][B][H] h1c, 1-step software pipeline of the x/Wih part) +
// removal of the per-step vmcnt(0) store-drain that was serializing the
// producer:
//  - x prefetch load is issued FIRST in the step (before any global store),
//    so the compiler's wait for it is a precise vmcnt(1), not a full drain
//    of the h1c stores (previously: stores issued before the load => the
//    load's s_waitcnt degenerated to vmcnt(0) every step, ~300-500 cyc).
//  - h1c stores converted from 4 scattered 2B stores/lane to ONE cooperative
//    coalesced 8B store/thread, re-reading hbuf[cur] (h(t-1), already
//    barrier-visible) at the top of step t. Off the dependency chain.
//  - flag protocol shifted: publish flag=t at t%8==7 ("h1c[0..t-1] done",
//    drained by the existing __syncthreads), epilogue publishes TT after
//    storing h(TT-1). Consumer waits 15 (was 16) / min(t+15,TT).
// Numerics identical to R7 (same MFMA/accumulation order): absmax 1.22e-4.

#define BB 1024
#define TT 512
#define FF 64
#define HH 128

typedef __attribute__((ext_vector_type(8))) short     v8s;  // 8 x bf16
typedef __attribute__((ext_vector_type(8))) _Float16  v8h;  // 8 x fp16
typedef __attribute__((ext_vector_type(4))) float     v4f;

__device__ __forceinline__ float sigmoidf_(float x) {
    return 1.0f / (1.0f + __expf(-x));
}
__device__ __forceinline__ float tanhf_(float x) {
    return 1.0f - 2.0f / (1.0f + __expf(2.0f * x));
}
__device__ __forceinline__ short bf16r(float v) {  // RNE fp32->bf16
    unsigned u = __float_as_uint(v);
    return (short)((u + 0x7FFFu + ((u >> 16) & 1u)) >> 16);
}
__device__ __forceinline__ float bf16tof(short s) {
    return __uint_as_float(((unsigned)(unsigned short)s) << 16);
}
// Barrier WITHOUT the compiler's vmcnt(0) drain (LDS ordering only).
__device__ __forceinline__ void light_barrier() {
    asm volatile("s_waitcnt lgkmcnt(0)\n\ts_barrier" ::: "memory");
}
// Bounded acquire-poll on a device-scope flag (RMW -> always coherent).
__device__ __forceinline__ void wait_flag_ge(int* f, int need) {
    for (int i = 0; i < 2000000; ++i) {
        int v = __hip_atomic_fetch_add(f, 0, __ATOMIC_ACQUIRE,
                                       __HIP_MEMORY_SCOPE_AGENT);
        if (v >= need) return;
        __builtin_amdgcn_s_sleep(4);
    }
}
// Truncation-based hi/lo bf16 split of two floats, packed into 2 u32
// (lo16 = elem a, hi16 = elem b).
__device__ __forceinline__ void split2(float a, float b,
                                       unsigned& hi, unsigned& lo) {
    unsigned ua = __float_as_uint(a), ub = __float_as_uint(b);
    hi = (ua >> 16) | (ub & 0xFFFF0000u);
    float ra = a - __uint_as_float(ua & 0xFFFF0000u);
    float rb = b - __uint_as_float(ub & 0xFFFF0000u);
    lo = (__float_as_uint(ra) >> 16) | (__float_as_uint(rb) & 0xFFFF0000u);
}

// MFMA 16x16x32 layouts: A/B: m(n)=lane&15, k=(lane>>4)*8+j ; C/D: col=lane&15,
// row=(lane>>4)*4+r.

__global__ __launch_bounds__(512, 1) void fused_lstm_kernel(
    const float* __restrict__ x,
    const float* __restrict__ Wih0, const float* __restrict__ Whh0,
    const float* __restrict__ bih0, const float* __restrict__ bhh0,
    const float* __restrict__ Wih1, const float* __restrict__ Whh1,
    const float* __restrict__ bih1, const float* __restrict__ bhh1,
    _Float16* __restrict__ h1c, float* __restrict__ hs, int* __restrict__ flags)
{
    const int tid = threadIdx.x;
    const int w = tid >> 6;
    const int l = tid & 63;
    const int lane16 = l & 15;
    const int quad = l >> 4;
    const int jh = 16 * w + lane16;
    const int hrow = tid >> 5;          // 0..15 (coop-store row)
    const int hcol = (tid & 31) * 4;    // 0..124 (coop-store col, x4 halves)

    __shared__ __align__(16) _Float16 hbuf[2][16 * 136];     // 8704 B
    __shared__ __align__(16) short    pool[3][2][16 * 72];   // 13824 B

    if (blockIdx.x < 64) {
        // ================= LAYER 0 (producer) =================
        const int tile = blockIdx.x;
        const long b0 = (long)tile * 16;
        int* flagp = &flags[tile];

        v8h bh[4][4];                 // Whh0 fp16 B-frags
        v8s bxh[4][2], bxl[4][2];     // Wih0 split-bf16 B-frags
        float bias[4];
        float c[4] = {0.f, 0.f, 0.f, 0.f};

#pragma unroll
        for (int g = 0; g < 4; ++g) {
            const int col = g * 128 + jh;
            bias[g] = bih0[col] + bhh0[col];
#pragma unroll
            for (int q = 0; q < 4; ++q) {
                const float* p = &Whh0[(long)col * HH + q * 32 + quad * 8];
                float4 u0 = *(const float4*)p;
                float4 u1 = *(const float4*)(p + 4);
                v8h t;
                t[0]=(_Float16)u0.x; t[1]=(_Float16)u0.y; t[2]=(_Float16)u0.z; t[3]=(_Float16)u0.w;
                t[4]=(_Float16)u1.x; t[5]=(_Float16)u1.y; t[6]=(_Float16)u1.z; t[7]=(_Float16)u1.w;
                bh[g][q] = t;
            }
#pragma unroll
            for (int q = 0; q < 2; ++q) {
                const float* p = &Wih0[(long)col * FF + q * 32 + quad * 8];
                float4 u0 = *(const float4*)p;
                float4 u1 = *(const float4*)(p + 4);
                float vv[8] = {u0.x,u0.y,u0.z,u0.w,u1.x,u1.y,u1.z,u1.w};
                v8s hi, lo;
#pragma unroll
                for (int e = 0; e < 8; ++e) {
                    short hbits = bf16r(vv[e]);
                    hi[e] = hbits;
                    lo[e] = bf16r(vv[e] - bf16tof(hbits));
                }
                bxh[g][q] = hi; bxl[g][q] = lo;
            }
        }

        for (int i = tid; i < 16 * 136; i += 512) hbuf[0][i] = (_Float16)0.0f;

        // ---- cooperative x staging: thread owns 2 floats of the 16x64 tile
        const int xr_row = tid >> 5;          // 0..15 (batch row within tile)
        const int xr_col = (tid & 31) * 2;    // 0..62, even
        const float* xp = &x[(b0 + xr_row) * TT * FF + xr_col];
        float2 x0v  = *(const float2*)xp;             // x(0)
        float2 x1v  = *(const float2*)(xp + FF);      // x(1)
        float2 xreg = *(const float2*)(xp + 2 * FF);  // x(2)
        xp += 3 * FF;                                 // -> x(3)
        {
            unsigned hi, lo; split2(x0v.x, x0v.y, hi, lo);
            *(unsigned*)&pool[0][0][xr_row * 72 + xr_col] = hi;
            *(unsigned*)&pool[0][1][xr_row * 72 + xr_col] = lo;
        }
        __syncthreads();

        // xacc(0) = bias + Wih0*x(0), from slot 0
        v4f xacc[4];
        {
            v8s xh[2], xl[2];
#pragma unroll
            for (int q = 0; q < 2; ++q) {
                xh[q] = *(const v8s*)&pool[0][0][lane16 * 72 + q * 32 + quad * 8];
                xl[q] = *(const v8s*)&pool[0][1][lane16 * 72 + q * 32 + quad * 8];
            }
#pragma unroll
            for (int g = 0; g < 4; ++g) {
                v4f a = {bias[g], bias[g], bias[g], bias[g]};
                a = __builtin_amdgcn_mfma_f32_16x16x32_bf16(xh[0], bxh[g][0], a, 0, 0, 0);
                a = __builtin_amdgcn_mfma_f32_16x16x32_bf16(xh[0], bxl[g][0], a, 0, 0, 0);
                a = __builtin_amdgcn_mfma_f32_16x16x32_bf16(xl[0], bxh[g][0], a, 0, 0, 0);
                a = __builtin_amdgcn_mfma_f32_16x16x32_bf16(xh[1], bxh[g][1], a, 0, 0, 0);
                a = __builtin_amdgcn_mfma_f32_16x16x32_bf16(xh[1], bxl[g][1], a, 0, 0, 0);
                a = __builtin_amdgcn_mfma_f32_16x16x32_bf16(xl[1], bxh[g][1], a, 0, 0, 0);
                xacc[g] = a;
            }
        }
        {   // stage x(1) into slot 1
            unsigned hi, lo; split2(x1v.x, x1v.y, hi, lo);
            *(unsigned*)&pool[1][0][xr_row * 72 + xr_col] = hi;
            *(unsigned*)&pool[1][1][xr_row * 72 + xr_col] = lo;
        }
        light_barrier();

        // coop-store target: h1c[t-1][b0+hrow][hcol], advanced each store
        _Float16* hcs = h1c + (b0 + hrow) * HH + hcol;
        int r1 = 1, r2 = 2;   // r1: slot holding x(t+1); r2: slot to write x(t+2)

        for (int t = 0; t < TT; ++t) {
            const int cur = t & 1, nxt = cur ^ 1;

            // ---- (1) EARLY x prefetch: issued before any store so its wait
            //      is a precise vmcnt(N), never a store drain ----
            float2 xnew = *(const float2*)xp;
            if (t < TT - 4) xp += FF;

            // ---- (2) cooperative coalesced h1c store of h(t-1) ----
            if (t > 0) {
                uint2 hv = *(const uint2*)&hbuf[cur][hrow * 136 + hcol];
                *(uint2*)hcs = hv;
                hcs += (long)BB * HH;
            }

            // ---- (3) critical path: recurrence MFMAs ----
            v8h ah[4];
#pragma unroll
            for (int q = 0; q < 4; ++q)
                ah[q] = *(const v8h*)&hbuf[cur][lane16 * 136 + q * 32 + quad * 8];

            v4f g0 = xacc[0], g1 = xacc[1], g2 = xacc[2], g3 = xacc[3];
#pragma unroll
            for (int q = 0; q < 4; ++q) {
                g0 = __builtin_amdgcn_mfma_f32_16x16x32_f16(ah[q], bh[0][q], g0, 0, 0, 0);
                g1 = __builtin_amdgcn_mfma_f32_16x16x32_f16(ah[q], bh[1][q], g1, 0, 0, 0);
                g2 = __builtin_amdgcn_mfma_f32_16x16x32_f16(ah[q], bh[2][q], g2, 0, 0, 0);
                g3 = __builtin_amdgcn_mfma_f32_16x16x32_f16(ah[q], bh[3][q], g3, 0, 0, 0);
            }

#pragma unroll
            for (int r = 0; r < 4; ++r) {
                float ig = sigmoidf_(g0[r]);
                float fg = sigmoidf_(g1[r]);
                float gg = tanhf_(g2[r]);
                float og = sigmoidf_(g3[r]);
                c[r] = fmaf(fg, c[r], ig * gg);
                float h = og * tanhf_(c[r]);
                const int m = quad * 4 + r;
                hbuf[nxt][m * 136 + jh] = (_Float16)h;   // LDS only
            }

            // ---- (4) off-path: xacc(t+1) = bias + Wih0*x(t+1) from slot r1 ----
            {
                v8s xh[2], xl[2];
#pragma unroll
                for (int q = 0; q < 2; ++q) {
                    xh[q] = *(const v8s*)&pool[r1][0][lane16 * 72 + q * 32 + quad * 8];
                    xl[q] = *(const v8s*)&pool[r1][1][lane16 * 72 + q * 32 + quad * 8];
                }
#pragma unroll
                for (int g = 0; g < 4; ++g) {
                    v4f a = {bias[g], bias[g], bias[g], bias[g]};
                    a = __builtin_amdgcn_mfma_f32_16x16x32_bf16(xh[0], bxh[g][0], a, 0, 0, 0);
                    a = __builtin_amdgcn_mfma_f32_16x16x32_bf16(xh[0], bxl[g][0], a, 0, 0, 0);
                    a = __builtin_amdgcn_mfma_f32_16x16x32_bf16(xl[0], bxh[g][0], a, 0, 0, 0);
                    a = __builtin_amdgcn_mfma_f32_16x16x32_bf16(xh[1], bxh[g][1], a, 0, 0, 0);
                    a = __builtin_amdgcn_mfma_f32_16x16x32_bf16(xh[1], bxl[g][1], a, 0, 0, 0);
                    a = __builtin_amdgcn_mfma_f32_16x16x32_bf16(xl[1], bxh[g][1], a, 0, 0, 0);
                    xacc[g] = a;
                }
            }

            // ---- stage x(t+2) into slot r2; roll prefetch register ----
            {
                unsigned hi, lo; split2(xreg.x, xreg.y, hi, lo);
                *(unsigned*)&pool[r2][0][xr_row * 72 + xr_col] = hi;
                *(unsigned*)&pool[r2][1][xr_row * 72 + xr_col] = lo;
            }
            xreg = xnew;

            {   // rotate slots: new r1 = r2, new r2 = the freed slot
                const int r0 = 3 - r1 - r2;
                r1 = r2; r2 = r0;
            }

            if ((t & 7) == 7) {
                __syncthreads();  // drains every wave's h1c stores (vmcnt 0)
                if (tid == 0)
                    __hip_atomic_store(flagp, t, __ATOMIC_RELEASE,
                                       __HIP_MEMORY_SCOPE_AGENT);
            } else {
                light_barrier();
            }
        }
        // epilogue: store h(TT-1) (lives in hbuf[TT&1 == 0]), publish TT
        {
            uint2 hv = *(const uint2*)&hbuf[0][hrow * 136 + hcol];
            *(uint2*)hcs = hv;
        }
        __syncthreads();
        if (tid == 0)
            __hip_atomic_store(flagp, TT, __ATOMIC_RELEASE,
                               __HIP_MEMORY_SCOPE_AGENT);
    } else {
        // ================= LAYER 1 (consumer) =================
        const int tile = blockIdx.x - 64;
        const long b0 = (long)tile * 16;
        int* flagp = &flags[tile];

        v8h bi[4][4], bh[4][4];
        float bias[4];
        float c[4] = {0.f, 0.f, 0.f, 0.f};

#pragma unroll
        for (int g = 0; g < 4; ++g) {
            const int col = g * 128 + jh;
            bias[g] = bih1[col] + bhh1[col];
#pragma unroll
            for (int q = 0; q < 4; ++q) {
                const float* pi = &Wih1[(long)col * HH + q * 32 + quad * 8];
                float4 u0 = *(const float4*)pi;
                float4 u1 = *(const float4*)(pi + 4);
                v8h t;
                t[0]=(_Float16)u0.x; t[1]=(_Float16)u0.y; t[2]=(_Float16)u0.z; t[3]=(_Float16)u0.w;
                t[4]=(_Float16)u1.x; t[5]=(_Float16)u1.y; t[6]=(_Float16)u1.z; t[7]=(_Float16)u1.w;
                bi[g][q] = t;
                const float* ph = &Whh1[(long)col * HH + q * 32 + quad * 8];
                float4 v0 = *(const float4*)ph;
                float4 v1 = *(const float4*)(ph + 4);
                v8h s;
                s[0]=(_Float16)v0.x; s[1]=(_Float16)v0.y; s[2]=(_Float16)v0.z; s[3]=(_Float16)v0.w;
                s[4]=(_Float16)v1.x; s[5]=(_Float16)v1.y; s[6]=(_Float16)v1.z; s[7]=(_Float16)v1.w;
                bh[g][q] = s;
            }
        }

        for (int i = tid; i < 16 * 136; i += 512) hbuf[0][i] = (_Float16)0.0f;

        _Float16* sb = (_Float16*)&pool[0][0][0];   // 3 slots, stride 2304 halves
        const int SBS = 2304;

        const int hr_row = tid >> 5;          // 0..15
        const int hr_col = (tid & 31) * 4;    // 0..124, multiple of 4

        // wait for h1[0..14] before the t=0 staging (covers prefetch window)
        if (tid == 0) wait_flag_ge(flagp, 15);
        __syncthreads();

        const _Float16* hp = h1c + (b0 + hr_row) * HH + hr_col;  // [t][B][H], t=0
        uint2 h0v  = *(const uint2*)hp;                    // h1(0)
        uint2 h1v  = *(const uint2*)(hp + (long)BB * HH);  // h1(1)
        uint2 hreg = *(const uint2*)(hp + 2L * BB * HH);   // h1(2)
        hp += 3L * BB * HH;                                // -> h1(3)
        *(uint2*)&sb[0 * SBS + hr_row * 136 + hr_col] = h0v;
        __syncthreads();

        // a1acc(0) = bias + Wih1*h1(0), from slot 0
        v4f a1acc[4];
        {
            v8h a1[4];
#pragma unroll
            for (int q = 0; q < 4; ++q)
                a1[q] = *(const v8h*)&sb[0 * SBS + lane16 * 136 + q * 32 + quad * 8];
#pragma unroll
            for (int g = 0; g < 4; ++g) {
                v4f a = {bias[g], bias[g], bias[g], bias[g]};
#pragma unroll
                for (int q = 0; q < 4; ++q)
                    a = __builtin_amdgcn_mfma_f32_16x16x32_f16(a1[q], bi[g][q], a, 0, 0, 0);
                a1acc[g] = a;
            }
        }
        *(uint2*)&sb[1 * SBS + hr_row * 136 + hr_col] = h1v;   // slot1 = h1(1)
        light_barrier();

        int r1 = 1, r2 = 2;
        for (int t = 0; t < TT; ++t) {
            if ((t & 7) == 0 && t > 0) {
                if (tid == 0) wait_flag_ge(flagp, (t + 15 < TT) ? t + 15 : TT);
                light_barrier();
            }
            const int cur = t & 1, nxt = cur ^ 1;

            // ---- critical path: recurrence MFMAs ----
            v8h a2[4];
#pragma unroll
            for (int q = 0; q < 4; ++q)
                a2[q] = *(const v8h*)&hbuf[cur][lane16 * 136 + q * 32 + quad * 8];

            v4f g0 = a1acc[0], g1 = a1acc[1], g2 = a1acc[2], g3 = a1acc[3];
#pragma unroll
            for (int q = 0; q < 4; ++q) {
                g0 = __builtin_amdgcn_mfma_f32_16x16x32_f16(a2[q], bh[0][q], g0, 0, 0, 0);
                g1 = __builtin_amdgcn_mfma_f32_16x16x32_f16(a2[q], bh[1][q], g1, 0, 0, 0);
                g2 = __builtin_amdgcn_mfma_f32_16x16x32_f16(a2[q], bh[2][q], g2, 0, 0, 0);
                g3 = __builtin_amdgcn_mfma_f32_16x16x32_f16(a2[q], bh[3][q], g3, 0, 0, 0);
            }

#pragma unroll
            for (int r = 0; r < 4; ++r) {
                float ig = sigmoidf_(g0[r]);
                float fg = sigmoidf_(g1[r]);
                float gg = tanhf_(g2[r]);
                float og = sigmoidf_(g3[r]);
                c[r] = fmaf(fg, c[r], ig * gg);
                float h = og * tanhf_(c[r]);
                const int m = quad * 4 + r;
                hbuf[nxt][m * 136 + jh] = (_Float16)h;
                if (t == TT - 1) hs[(b0 + m) * HH + jh] = h;
            }

            // ---- off-path: a1acc(t+1) = bias + Wih1*h1(t+1) from slot r1 ----
            {
                v8h a1[4];
#pragma unroll
                for (int q = 0; q < 4; ++q)
                    a1[q] = *(const v8h*)&sb[r1 * SBS + lane16 * 136 + q * 32 + quad * 8];
#pragma unroll
                for (int g = 0; g < 4; ++g) {
                    v4f a = {bias[g], bias[g], bias[g], bias[g]};
#pragma unroll
                    for (int q = 0; q < 4; ++q)
                        a = __builtin_amdgcn_mfma_f32_16x16x32_f16(a1[q], bi[g][q], a, 0, 0, 0);
                    a1acc[g] = a;
                }
            }

            // ---- stage h1(t+2) into slot r2; prefetch h1(t+3) ----
            *(uint2*)&sb[r2 * SBS + hr_row * 136 + hr_col] = hreg;
            hreg = *(const uint2*)hp;
            if (t < TT - 4) hp += (long)BB * HH;

            {
                const int r0 = 3 - r1 - r2;
                r1 = r2; r2 = r0;
            }

            light_barrier();
        }
    }
}

// ---------------- FC head: out = relu(h @ fc1^T + b1) @ fc2^T + b2 ----------
__global__ __launch_bounds__(64) void head_kernel(
    const float* __restrict__ h, const float* __restrict__ w1,
    const float* __restrict__ b1, const float* __restrict__ w2,
    const float* __restrict__ b2, float* __restrict__ out)
{
    const int b = blockIdx.x;
    const int n = threadIdx.x;
    float acc = b1[n];
#pragma unroll
    for (int k = 0; k < HH; ++k)
        acc = fmaf(w1[n * HH + k], h[b * HH + k], acc);
    float v = fmaxf(acc, 0.0f) * w2[n];
#pragma unroll
    for (int off = 32; off > 0; off >>= 1)
        v += __shfl_down(v, off);
    if (n == 0) out[b] = v + b2[0];
}

extern "C" void kernel_launch(void* const* d_in, const int* in_sizes, int n_in,
                              void* d_out, int out_size, void* d_ws, size_t ws_size,
                              hipStream_t stream)
{
    const float* x    = (const float*)d_in[0];
    const float* Wih0 = (const float*)d_in[1];
    const float* Whh0 = (const float*)d_in[2];
    const float* bih0 = (const float*)d_in[3];
    const float* bhh0 = (const float*)d_in[4];
    const float* Wih1 = (const float*)d_in[5];
    const float* Whh1 = (const float*)d_in[6];
    const float* bih1 = (const float*)d_in[7];
    const float* bhh1 = (const float*)d_in[8];
    const float* w1   = (const float*)d_in[9];
    const float* b1   = (const float*)d_in[10];
    const float* w2   = (const float*)d_in[11];
    const float* b2   = (const float*)d_in[12];
    float* out = (float*)d_out;

    char* ws = (char*)d_ws;
    _Float16* h1c = (_Float16*)ws;                              // 134 MB, [t][B][H]
    float* hs  = (float*)(ws + (size_t)BB * TT * HH * sizeof(_Float16));
    int* flags = (int*)(ws + (size_t)BB * TT * HH * sizeof(_Float16)
                           + (size_t)BB * HH * sizeof(float));

    hipMemsetAsync(flags, 0, 64 * sizeof(int), stream);

    fused_lstm_kernel<<<128, 512, 0, stream>>>(
        x, Wih0, Whh0, bih0, bhh0, Wih1, Whh1, bih1, bhh1, h1c, hs, flags);
    head_kernel<<<BB, 64, 0, stream>>>(hs, w1, b1, w2, b2, out);
}

// Round 4
// 886.480 us; speedup vs baseline: 1.2991x; 1.2991x over previous
//
#include <hip/hip_runtime.h>
#include <math.h>

// 2-layer LSTM (B=1024,T=512,F=64,H=128) + FC head.
// R9: R8 structure (layer-pipelined producer/consumer, cooperative LDS
// staging, [t][B][H] h1c, coalesced coop h1c store, 1-step software pipeline
// of the x/Wih part) + VALU-issue diet:
//  - gate nonlinearities via v_rcp (__builtin_amdgcn_rcpf) instead of IEEE
//    divide: hipcc without fast-math emits ~8-instr div sequences; 20 of
//    them per lane per step was the largest hidden VALU consumer.
//  - weights/biases prescaled by log2e (g-gate row by 2*log2e) at frag-prep
//    time -> gates arrive in exp2 domain; exp2(-x) uses the free VOP3 neg
//    modifier. sigma(x)=rcp(1+exp2(-x~)), tanh via 1-2*rcp(1+exp2(x~)).
//  - t-loop unrolled x2 with 2-slot parity staging pools (3-slot rotation
//    removed; write-slot was last READ a full barrier earlier -> race-free):
//    every LDS index is now a compile-time constant, killing per-step
//    address arithmetic + slot-rotation VALU.
// Sync protocol identical to R8 (flag=t at t%8==7, epilogue TT; consumer
// waits 15 / min(t+15,TT)).

#define BB 1024
#define TT 512
#define FF 64
#define HH 128
#define LOG2E 1.44269504088896340736f
#define TWOLOG2E 2.88539008177792681472f

typedef __attribute__((ext_vector_type(8))) short     v8s;  // 8 x bf16
typedef __attribute__((ext_vector_type(8))) _Float16  v8h;  // 8 x fp16
typedef __attribute__((ext_vector_type(4))) float     v4f;

__device__ __forceinline__ short bf16r(float v) {  // RNE fp32->bf16
    unsigned u = __float_as_uint(v);
    return (short)((u + 0x7FFFu + ((u >> 16) & 1u)) >> 16);
}
__device__ __forceinline__ float bf16tof(short s) {
    return __uint_as_float(((unsigned)(unsigned short)s) << 16);
}
// rcp(1 + exp2(y)) : core of exp2-domain sigmoid/tanh. v_exp_f32 + v_add +
// v_rcp, no IEEE-div sequence.
__device__ __forceinline__ float rcp1p(float y) {
    return __builtin_amdgcn_rcpf(1.0f + __builtin_exp2f(y));
}
// Barrier WITHOUT the compiler's vmcnt(0) drain (LDS ordering only).
__device__ __forceinline__ void light_barrier() {
    asm volatile("s_waitcnt lgkmcnt(0)\n\ts_barrier" ::: "memory");
}
// Bounded acquire-poll on a device-scope flag (RMW -> always coherent).
__device__ __forceinline__ void wait_flag_ge(int* f, int need) {
    for (int i = 0; i < 2000000; ++i) {
        int v = __hip_atomic_fetch_add(f, 0, __ATOMIC_ACQUIRE,
                                       __HIP_MEMORY_SCOPE_AGENT);
        if (v >= need) return;
        __builtin_amdgcn_s_sleep(4);
    }
}
// Truncation-based hi/lo bf16 split of two floats, packed into 2 u32
// (lo16 = elem a, hi16 = elem b).
__device__ __forceinline__ void split2(float a, float b,
                                       unsigned& hi, unsigned& lo) {
    unsigned ua = __float_as_uint(a), ub = __float_as_uint(b);
    hi = (ua >> 16) | (ub & 0xFFFF0000u);
    float ra = a - __uint_as_float(ua & 0xFFFF0000u);
    float rb = b - __uint_as_float(ub & 0xFFFF0000u);
    lo = (__float_as_uint(ra) >> 16) | (__float_as_uint(rb) & 0xFFFF0000u);
}

// MFMA 16x16x32 layouts: A/B: m(n)=lane&15, k=(lane>>4)*8+j ; C/D: col=lane&15,
// row=(lane>>4)*4+r.

// ---- one producer LSTM step; all LDS slot indices compile-time ----
#define PROD_STEP(CUR, NXT, RD, WR, tv, PUB)                                   \
  {                                                                            \
    float2 xnew = *(const float2*)xp;                                          \
    if ((tv) < TT - 4) xp += FF;                                               \
    if ((tv) > 0) {                                                            \
      uint2 hv = *(const uint2*)&hbuf[CUR][hrow * 136 + hcol];                 \
      *(uint2*)hcs = hv;                                                       \
      hcs += (long)BB * HH;                                                    \
    }                                                                          \
    v8h ah[4];                                                                 \
    _Pragma("unroll") for (int q = 0; q < 4; ++q)                              \
        ah[q] = *(const v8h*)&hbuf[CUR][lane16 * 136 + q * 32 + quad * 8];     \
    v4f g0 = xacc[0], g1 = xacc[1], g2 = xacc[2], g3 = xacc[3];                \
    _Pragma("unroll") for (int q = 0; q < 4; ++q) {                            \
      g0 = __builtin_amdgcn_mfma_f32_16x16x32_f16(ah[q], bh[0][q], g0, 0, 0, 0);\
      g1 = __builtin_amdgcn_mfma_f32_16x16x32_f16(ah[q], bh[1][q], g1, 0, 0, 0);\
      g2 = __builtin_amdgcn_mfma_f32_16x16x32_f16(ah[q], bh[2][q], g2, 0, 0, 0);\
      g3 = __builtin_amdgcn_mfma_f32_16x16x32_f16(ah[q], bh[3][q], g3, 0, 0, 0);\
    }                                                                          \
    _Pragma("unroll") for (int r = 0; r < 4; ++r) {                            \
      float ig = rcp1p(-g0[r]);                                                \
      float fg = rcp1p(-g1[r]);                                                \
      float gt = fmaf(-2.0f, rcp1p(g2[r]), 1.0f);                              \
      float og = rcp1p(-g3[r]);                                                \
      c[r] = fmaf(fg, c[r], ig * gt);                                          \
      float th = fmaf(-2.0f, rcp1p(TWOLOG2E * c[r]), 1.0f);                    \
      float h = og * th;                                                       \
      hbuf[NXT][(quad * 4 + r) * 136 + jh] = (_Float16)h;                      \
    }                                                                          \
    {                                                                          \
      v8s xh[2], xl[2];                                                        \
      _Pragma("unroll") for (int q = 0; q < 2; ++q) {                          \
        xh[q] = *(const v8s*)&pool[RD][0][lane16 * 72 + q * 32 + quad * 8];    \
        xl[q] = *(const v8s*)&pool[RD][1][lane16 * 72 + q * 32 + quad * 8];    \
      }                                                                        \
      _Pragma("unroll") for (int g = 0; g < 4; ++g) {                          \
        v4f a = {bias[g], bias[g], bias[g], bias[g]};                          \
        a = __builtin_amdgcn_mfma_f32_16x16x32_bf16(xh[0], bxh[g][0], a, 0, 0, 0);\
        a = __builtin_amdgcn_mfma_f32_16x16x32_bf16(xh[0], bxl[g][0], a, 0, 0, 0);\
        a = __builtin_amdgcn_mfma_f32_16x16x32_bf16(xl[0], bxh[g][0], a, 0, 0, 0);\
        a = __builtin_amdgcn_mfma_f32_16x16x32_bf16(xh[1], bxh[g][1], a, 0, 0, 0);\
        a = __builtin_amdgcn_mfma_f32_16x16x32_bf16(xh[1], bxl[g][1], a, 0, 0, 0);\
        a = __builtin_amdgcn_mfma_f32_16x16x32_bf16(xl[1], bxh[g][1], a, 0, 0, 0);\
        xacc[g] = a;                                                           \
      }                                                                        \
    }                                                                          \
    {                                                                          \
      unsigned hi_, lo_;                                                       \
      split2(xreg.x, xreg.y, hi_, lo_);                                        \
      *(unsigned*)&pool[WR][0][xr_row * 72 + xr_col] = hi_;                    \
      *(unsigned*)&pool[WR][1][xr_row * 72 + xr_col] = lo_;                    \
    }                                                                          \
    xreg = xnew;                                                               \
    if (PUB) {                                                                 \
      __syncthreads();                                                         \
      if (tid == 0)                                                            \
        __hip_atomic_store(flagp, (tv), __ATOMIC_RELEASE,                      \
                           __HIP_MEMORY_SCOPE_AGENT);                          \
    } else {                                                                   \
      light_barrier();                                                         \
    }                                                                          \
  }

// ---- one consumer LSTM step ----
#define CONS_STEP(CUR, NXT, RD, WR, tv, DOWAIT)                                \
  {                                                                            \
    if (DOWAIT) {                                                              \
      if (tid == 0) wait_flag_ge(flagp, ((tv) + 15 < TT) ? (tv) + 15 : TT);    \
      light_barrier();                                                         \
    }                                                                          \
    v8h a2[4];                                                                 \
    _Pragma("unroll") for (int q = 0; q < 4; ++q)                              \
        a2[q] = *(const v8h*)&hbuf[CUR][lane16 * 136 + q * 32 + quad * 8];     \
    v4f g0 = a1acc[0], g1 = a1acc[1], g2 = a1acc[2], g3 = a1acc[3];            \
    _Pragma("unroll") for (int q = 0; q < 4; ++q) {                            \
      g0 = __builtin_amdgcn_mfma_f32_16x16x32_f16(a2[q], bh[0][q], g0, 0, 0, 0);\
      g1 = __builtin_amdgcn_mfma_f32_16x16x32_f16(a2[q], bh[1][q], g1, 0, 0, 0);\
      g2 = __builtin_amdgcn_mfma_f32_16x16x32_f16(a2[q], bh[2][q], g2, 0, 0, 0);\
      g3 = __builtin_amdgcn_mfma_f32_16x16x32_f16(a2[q], bh[3][q], g3, 0, 0, 0);\
    }                                                                          \
    _Pragma("unroll") for (int r = 0; r < 4; ++r) {                            \
      float ig = rcp1p(-g0[r]);                                                \
      float fg = rcp1p(-g1[r]);                                                \
      float gt = fmaf(-2.0f, rcp1p(g2[r]), 1.0f);                              \
      float og = rcp1p(-g3[r]);                                                \
      c[r] = fmaf(fg, c[r], ig * gt);                                          \
      float th = fmaf(-2.0f, rcp1p(TWOLOG2E * c[r]), 1.0f);                    \
      float h = og * th;                                                       \
      hbuf[NXT][(quad * 4 + r) * 136 + jh] = (_Float16)h;                      \
      if ((tv) == TT - 1) hs[(b0 + quad * 4 + r) * HH + jh] = h;               \
    }                                                                          \
    {                                                                          \
      v8h a1[4];                                                               \
      _Pragma("unroll") for (int q = 0; q < 4; ++q)                            \
          a1[q] = *(const v8h*)&sb[(RD) * 2176 + lane16 * 136 + q * 32 + quad * 8];\
      _Pragma("unroll") for (int g = 0; g < 4; ++g) {                          \
        v4f a = {bias[g], bias[g], bias[g], bias[g]};                          \
        _Pragma("unroll") for (int q = 0; q < 4; ++q)                          \
            a = __builtin_amdgcn_mfma_f32_16x16x32_f16(a1[q], bi[g][q], a, 0, 0, 0);\
        a1acc[g] = a;                                                          \
      }                                                                        \
    }                                                                          \
    *(uint2*)&sb[(WR) * 2176 + hr_row * 136 + hr_col] = hreg;                  \
    hreg = *(const uint2*)hp;                                                  \
    if ((tv) < TT - 4) hp += (long)BB * HH;                                    \
    light_barrier();                                                           \
  }

__global__ __launch_bounds__(512, 1) void fused_lstm_kernel(
    const float* __restrict__ x,
    const float* __restrict__ Wih0, const float* __restrict__ Whh0,
    const float* __restrict__ bih0, const float* __restrict__ bhh0,
    const float* __restrict__ Wih1, const float* __restrict__ Whh1,
    const float* __restrict__ bih1, const float* __restrict__ bhh1,
    _Float16* __restrict__ h1c, float* __restrict__ hs, int* __restrict__ flags)
{
    const int tid = threadIdx.x;
    const int w = tid >> 6;
    const int l = tid & 63;
    const int lane16 = l & 15;
    const int quad = l >> 4;
    const int jh = 16 * w + lane16;
    const int hrow = tid >> 5;          // 0..15 (coop-store row)
    const int hcol = (tid & 31) * 4;    // 0..124 (coop-store col, x4 halves)

    __shared__ __align__(16) _Float16 hbuf[2][16 * 136];     // 8704 B
    __shared__ __align__(16) short    pool[2][2][16 * 72];   // 9216 B

    if (blockIdx.x < 64) {
        // ================= LAYER 0 (producer) =================
        const int tile = blockIdx.x;
        const long b0 = (long)tile * 16;
        int* flagp = &flags[tile];

        v8h bh[4][4];                 // Whh0 fp16 B-frags (log2e-scaled)
        v8s bxh[4][2], bxl[4][2];     // Wih0 split-bf16 B-frags (log2e-scaled)
        float bias[4];
        float c[4] = {0.f, 0.f, 0.f, 0.f};

#pragma unroll
        for (int g = 0; g < 4; ++g) {
            const int col = g * 128 + jh;
            const float sg = (g == 2) ? TWOLOG2E : LOG2E;   // g-gate: tanh(2x) form
            bias[g] = (bih0[col] + bhh0[col]) * sg;
#pragma unroll
            for (int q = 0; q < 4; ++q) {
                const float* p = &Whh0[(long)col * HH + q * 32 + quad * 8];
                float4 u0 = *(const float4*)p;
                float4 u1 = *(const float4*)(p + 4);
                v8h t;
                t[0]=(_Float16)(u0.x*sg); t[1]=(_Float16)(u0.y*sg);
                t[2]=(_Float16)(u0.z*sg); t[3]=(_Float16)(u0.w*sg);
                t[4]=(_Float16)(u1.x*sg); t[5]=(_Float16)(u1.y*sg);
                t[6]=(_Float16)(u1.z*sg); t[7]=(_Float16)(u1.w*sg);
                bh[g][q] = t;
            }
#pragma unroll
            for (int q = 0; q < 2; ++q) {
                const float* p = &Wih0[(long)col * FF + q * 32 + quad * 8];
                float4 u0 = *(const float4*)p;
                float4 u1 = *(const float4*)(p + 4);
                float vv[8] = {u0.x,u0.y,u0.z,u0.w,u1.x,u1.y,u1.z,u1.w};
                v8s hi, lo;
#pragma unroll
                for (int e = 0; e < 8; ++e) {
                    float vs = vv[e] * sg;
                    short hbits = bf16r(vs);
                    hi[e] = hbits;
                    lo[e] = bf16r(vs - bf16tof(hbits));
                }
                bxh[g][q] = hi; bxl[g][q] = lo;
            }
        }

        for (int i = tid; i < 16 * 136; i += 512) hbuf[0][i] = (_Float16)0.0f;

        // ---- cooperative x staging: thread owns 2 floats of the 16x64 tile
        const int xr_row = tid >> 5;          // 0..15 (batch row within tile)
        const int xr_col = (tid & 31) * 2;    // 0..62, even
        const float* xp = &x[(b0 + xr_row) * TT * FF + xr_col];
        float2 x0v  = *(const float2*)xp;             // x(0)
        float2 x1v  = *(const float2*)(xp + FF);      // x(1)
        float2 xreg = *(const float2*)(xp + 2 * FF);  // x(2)
        xp += 3 * FF;                                 // -> x(3)
        {
            unsigned hi, lo; split2(x0v.x, x0v.y, hi, lo);
            *(unsigned*)&pool[0][0][xr_row * 72 + xr_col] = hi;
            *(unsigned*)&pool[0][1][xr_row * 72 + xr_col] = lo;
        }
        __syncthreads();

        // xacc(0) = bias + Wih0*x(0), from slot 0
        v4f xacc[4];
        {
            v8s xh[2], xl[2];
#pragma unroll
            for (int q = 0; q < 2; ++q) {
                xh[q] = *(const v8s*)&pool[0][0][lane16 * 72 + q * 32 + quad * 8];
                xl[q] = *(const v8s*)&pool[0][1][lane16 * 72 + q * 32 + quad * 8];
            }
#pragma unroll
            for (int g = 0; g < 4; ++g) {
                v4f a = {bias[g], bias[g], bias[g], bias[g]};
                a = __builtin_amdgcn_mfma_f32_16x16x32_bf16(xh[0], bxh[g][0], a, 0, 0, 0);
                a = __builtin_amdgcn_mfma_f32_16x16x32_bf16(xh[0], bxl[g][0], a, 0, 0, 0);
                a = __builtin_amdgcn_mfma_f32_16x16x32_bf16(xl[0], bxh[g][0], a, 0, 0, 0);
                a = __builtin_amdgcn_mfma_f32_16x16x32_bf16(xh[1], bxh[g][1], a, 0, 0, 0);
                a = __builtin_amdgcn_mfma_f32_16x16x32_bf16(xh[1], bxl[g][1], a, 0, 0, 0);
                a = __builtin_amdgcn_mfma_f32_16x16x32_bf16(xl[1], bxh[g][1], a, 0, 0, 0);
                xacc[g] = a;
            }
        }
        {   // stage x(1) into slot 1
            unsigned hi, lo; split2(x1v.x, x1v.y, hi, lo);
            *(unsigned*)&pool[1][0][xr_row * 72 + xr_col] = hi;
            *(unsigned*)&pool[1][1][xr_row * 72 + xr_col] = lo;
        }
        light_barrier();

        // coop-store target: h1c[t-1][b0+hrow][hcol], advanced each store
        _Float16* hcs = h1c + (b0 + hrow) * HH + hcol;

        // steady state: at step t read x(t+1) from slot (t+1)&1,
        // write x(t+2) into slot t&1 (last read a full barrier ago).
        for (int tp = 0; tp < TT / 2; ++tp) {
            PROD_STEP(0, 1, 1, 0, 2 * tp,     false);
            PROD_STEP(1, 0, 0, 1, 2 * tp + 1, ((tp & 3) == 3));
        }
        // epilogue: store h(TT-1) (lives in hbuf[0]), publish TT
        {
            uint2 hv = *(const uint2*)&hbuf[0][hrow * 136 + hcol];
            *(uint2*)hcs = hv;
        }
        __syncthreads();
        if (tid == 0)
            __hip_atomic_store(flagp, TT, __ATOMIC_RELEASE,
                               __HIP_MEMORY_SCOPE_AGENT);
    } else {
        // ================= LAYER 1 (consumer) =================
        const int tile = blockIdx.x - 64;
        const long b0 = (long)tile * 16;
        int* flagp = &flags[tile];

        v8h bi[4][4], bh[4][4];      // log2e-scaled
        float bias[4];
        float c[4] = {0.f, 0.f, 0.f, 0.f};

#pragma unroll
        for (int g = 0; g < 4; ++g) {
            const int col = g * 128 + jh;
            const float sg = (g == 2) ? TWOLOG2E : LOG2E;
            bias[g] = (bih1[col] + bhh1[col]) * sg;
#pragma unroll
            for (int q = 0; q < 4; ++q) {
                const float* pi = &Wih1[(long)col * HH + q * 32 + quad * 8];
                float4 u0 = *(const float4*)pi;
                float4 u1 = *(const float4*)(pi + 4);
                v8h t;
                t[0]=(_Float16)(u0.x*sg); t[1]=(_Float16)(u0.y*sg);
                t[2]=(_Float16)(u0.z*sg); t[3]=(_Float16)(u0.w*sg);
                t[4]=(_Float16)(u1.x*sg); t[5]=(_Float16)(u1.y*sg);
                t[6]=(_Float16)(u1.z*sg); t[7]=(_Float16)(u1.w*sg);
                bi[g][q] = t;
                const float* ph = &Whh1[(long)col * HH + q * 32 + quad * 8];
                float4 v0 = *(const float4*)ph;
                float4 v1 = *(const float4*)(ph + 4);
                v8h s;
                s[0]=(_Float16)(v0.x*sg); s[1]=(_Float16)(v0.y*sg);
                s[2]=(_Float16)(v0.z*sg); s[3]=(_Float16)(v0.w*sg);
                s[4]=(_Float16)(v1.x*sg); s[5]=(_Float16)(v1.y*sg);
                s[6]=(_Float16)(v1.z*sg); s[7]=(_Float16)(v1.w*sg);
                bh[g][q] = s;
            }
        }

        for (int i = tid; i < 16 * 136; i += 512) hbuf[0][i] = (_Float16)0.0f;

        _Float16* sb = (_Float16*)&pool[0][0][0];   // 2 slots, stride 2176 halves

        const int hr_row = tid >> 5;          // 0..15
        const int hr_col = (tid & 31) * 4;    // 0..124, multiple of 4

        // wait for h1[0..14] before the t=0 staging (covers prefetch window)
        if (tid == 0) wait_flag_ge(flagp, 15);
        __syncthreads();

        const _Float16* hp = h1c + (b0 + hr_row) * HH + hr_col;  // [t][B][H], t=0
        uint2 h0v  = *(const uint2*)hp;                    // h1(0)
        uint2 h1v  = *(const uint2*)(hp + (long)BB * HH);  // h1(1)
        uint2 hreg = *(const uint2*)(hp + 2L * BB * HH);   // h1(2)
        hp += 3L * BB * HH;                                // -> h1(3)
        *(uint2*)&sb[0 * 2176 + hr_row * 136 + hr_col] = h0v;
        __syncthreads();

        // a1acc(0) = bias + Wih1*h1(0), from slot 0
        v4f a1acc[4];
        {
            v8h a1[4];
#pragma unroll
            for (int q = 0; q < 4; ++q)
                a1[q] = *(const v8h*)&sb[0 * 2176 + lane16 * 136 + q * 32 + quad * 8];
#pragma unroll
            for (int g = 0; g < 4; ++g) {
                v4f a = {bias[g], bias[g], bias[g], bias[g]};
#pragma unroll
                for (int q = 0; q < 4; ++q)
                    a = __builtin_amdgcn_mfma_f32_16x16x32_f16(a1[q], bi[g][q], a, 0, 0, 0);
                a1acc[g] = a;
            }
        }
        *(uint2*)&sb[1 * 2176 + hr_row * 136 + hr_col] = h1v;   // slot1 = h1(1)
        light_barrier();

        for (int tp = 0; tp < TT / 2; ++tp) {
            CONS_STEP(0, 1, 1, 0, 2 * tp,     ((tp & 3) == 0 && tp > 0));
            CONS_STEP(1, 0, 0, 1, 2 * tp + 1, false);
        }
    }
}

// ---------------- FC head: out = relu(h @ fc1^T + b1) @ fc2^T + b2 ----------
__global__ __launch_bounds__(64) void head_kernel(
    const float* __restrict__ h, const float* __restrict__ w1,
    const float* __restrict__ b1, const float* __restrict__ w2,
    const float* __restrict__ b2, float* __restrict__ out)
{
    const int b = blockIdx.x;
    const int n = threadIdx.x;
    float acc = b1[n];
#pragma unroll
    for (int k = 0; k < HH; ++k)
        acc = fmaf(w1[n * HH + k], h[b * HH + k], acc);
    float v = fmaxf(acc, 0.0f) * w2[n];
#pragma unroll
    for (int off = 32; off > 0; off >>= 1)
        v += __shfl_down(v, off);
    if (n == 0) out[b] = v + b2[0];
}

extern "C" void kernel_launch(void* const* d_in, const int* in_sizes, int n_in,
                              void* d_out, int out_size, void* d_ws, size_t ws_size,
                              hipStream_t stream)
{
    const float* x    = (const float*)d_in[0];
    const float* Wih0 = (const float*)d_in[1];
    const float* Whh0 = (const float*)d_in[2];
    const float* bih0 = (const float*)d_in[3];
    const float* bhh0 = (const float*)d_in[4];
    const float* Wih1 = (const float*)d_in[5];
    const float* Whh1 = (const float*)d_in[6];
    const float* bih1 = (const float*)d_in[7];
    const float* bhh1 = (const float*)d_in[8];
    const float* w1   = (const float*)d_in[9];
    const float* b1   = (const float*)d_in[10];
    const float* w2   = (const float*)d_in[11];
    const float* b2   = (const float*)d_in[12];
    float* out = (float*)d_out;

    char* ws = (char*)d_ws;
    _Float16* h1c = (_Float16*)ws;                              // 134 MB, [t][B][H]
    float* hs  = (float*)(ws + (size_t)BB * TT * HH * sizeof(_Float16));
    int* flags = (int*)(ws + (size_t)BB * TT * HH * sizeof(_Float16)
                           + (size_t)BB * HH * sizeof(float));

    hipMemsetAsync(flags, 0, 64 * sizeof(int), stream);

    fused_lstm_kernel<<<128, 512, 0, stream>>>(
        x, Wih0, Whh0, bih0, bhh0, Wih1, Whh1, bih1, bhh1, h1c, hs, flags);
    head_kernel<<<BB, 64, 0, stream>>>(hs, w1, b1, w2, b2, out);
}

// Round 5
// 873.646 us; speedup vs baseline: 1.3181x; 1.0147x over previous
//
#include <hip/hip_runtime.h>
#include <math.h>

// 2-layer LSTM (B=1024,T=512,F=64,H=128) + FC head.
// R10: WAVE-SPECIALIZED 1024-thread blocks (4 waves/SIMD, was 2).
//  Block = 16 waves: waves 0-7 "rec" run ONLY the recurrence
//  (ds_read fp32 gate-partials + h-frags -> 16 h-MFMAs -> gates -> hbuf),
//  waves 8-15 "helper" run everything recurrence-independent ONE STEP AHEAD:
//  x/Wih MFMAs (producer: 24 split-bf16; consumer: 16 fp16 on h1) writing
//  bias+x-part fp32 partials into a transposed padded LDS buffer
//  xbuf[2][512][20] (col-major, stride 20 dwords: 16B-aligned b128 rows,
//  ~2-way banks), plus x/h1 staging, split2, h1c coop-store, prefetches.
//  - rec accumulator init = 4x ds_read_b128 of xbuf (replaces bias-splat +
//    24 MFMAs in-stream): same accumulation order -> numerics identical.
//  - per-SIMD: 2 lean rec waves + 2 light helper waves: lower total issue
//    than R9's 2 fat waves, 2x the latency hiding.
//  - helper waves absorb the vmcnt(0) drain at publish epochs (heavy
//    barrier); rec waves only ever lgkmcnt-barrier.
//  Sync protocol identical to R9 (flag=t at t%8==7, epilogue TT; consumer
//  waits 15 / min(t+15,TT); producer never waits on consumer).

#define BB 1024
#define TT 512
#define FF 64
#define HH 128
#define LOG2E 1.44269504088896340736f
#define TWOLOG2E 2.88539008177792681472f

typedef __attribute__((ext_vector_type(8))) short     v8s;  // 8 x bf16
typedef __attribute__((ext_vector_type(8))) _Float16  v8h;  // 8 x fp16
typedef __attribute__((ext_vector_type(4))) float     v4f;

__device__ __forceinline__ short bf16r(float v) {  // RNE fp32->bf16
    unsigned u = __float_as_uint(v);
    return (short)((u + 0x7FFFu + ((u >> 16) & 1u)) >> 16);
}
__device__ __forceinline__ float bf16tof(short s) {
    return __uint_as_float(((unsigned)(unsigned short)s) << 16);
}
// rcp(1 + exp2(y)) : core of exp2-domain sigmoid/tanh.
__device__ __forceinline__ float rcp1p(float y) {
    return __builtin_amdgcn_rcpf(1.0f + __builtin_exp2f(y));
}
// Barrier WITHOUT vmcnt drain (LDS ordering only).
__device__ __forceinline__ void light_barrier() {
    asm volatile("s_waitcnt lgkmcnt(0)\n\ts_barrier" ::: "memory");
}
// Barrier WITH full drain (helper waves at publish epochs).
__device__ __forceinline__ void heavy_barrier() {
    asm volatile("s_waitcnt vmcnt(0) lgkmcnt(0)\n\ts_barrier" ::: "memory");
}
// Bounded acquire-poll on a device-scope flag.
__device__ __forceinline__ void wait_flag_ge(int* f, int need) {
    for (int i = 0; i < 2000000; ++i) {
        int v = __hip_atomic_fetch_add(f, 0, __ATOMIC_ACQUIRE,
                                       __HIP_MEMORY_SCOPE_AGENT);
        if (v >= need) return;
        __builtin_amdgcn_s_sleep(4);
    }
}
// Truncation-based hi/lo bf16 split of two floats, packed into 2 u32.
__device__ __forceinline__ void split2(float a, float b,
                                       unsigned& hi, unsigned& lo) {
    unsigned ua = __float_as_uint(a), ub = __float_as_uint(b);
    hi = (ua >> 16) | (ub & 0xFFFF0000u);
    float ra = a - __uint_as_float(ua & 0xFFFF0000u);
    float rb = b - __uint_as_float(ub & 0xFFFF0000u);
    lo = (__float_as_uint(ra) >> 16) | (__float_as_uint(rb) & 0xFFFF0000u);
}

// MFMA 16x16x32 layouts: A/B: m(n)=lane&15, k=(lane>>4)*8+j ; C/D: col=lane&15,
// row=(lane>>4)*4+r.

// ---- recurrence step (rec waves). STORE_HS: consumer writes hs at TT-1. ----
#define REC_STEP(CUR, NXT, tv, STORE_HS)                                       \
  {                                                                            \
    v4f g0 = *(const v4f*)&xbuf[CUR][(0 * 128 + jh) * 20 + quad * 4];          \
    v4f g1 = *(const v4f*)&xbuf[CUR][(1 * 128 + jh) * 20 + quad * 4];          \
    v4f g2 = *(const v4f*)&xbuf[CUR][(2 * 128 + jh) * 20 + quad * 4];          \
    v4f g3 = *(const v4f*)&xbuf[CUR][(3 * 128 + jh) * 20 + quad * 4];          \
    v8h ah[4];                                                                 \
    _Pragma("unroll") for (int q = 0; q < 4; ++q)                              \
        ah[q] = *(const v8h*)&hbuf[CUR][lane16 * 136 + q * 32 + quad * 8];     \
    _Pragma("unroll") for (int q = 0; q < 4; ++q) {                            \
      g0 = __builtin_amdgcn_mfma_f32_16x16x32_f16(ah[q], bh[0][q], g0, 0, 0, 0);\
      g1 = __builtin_amdgcn_mfma_f32_16x16x32_f16(ah[q], bh[1][q], g1, 0, 0, 0);\
      g2 = __builtin_amdgcn_mfma_f32_16x16x32_f16(ah[q], bh[2][q], g2, 0, 0, 0);\
      g3 = __builtin_amdgcn_mfma_f32_16x16x32_f16(ah[q], bh[3][q], g3, 0, 0, 0);\
    }                                                                          \
    _Pragma("unroll") for (int r = 0; r < 4; ++r) {                            \
      float ig = rcp1p(-g0[r]);                                                \
      float fg = rcp1p(-g1[r]);                                                \
      float gt = fmaf(-2.0f, rcp1p(g2[r]), 1.0f);                              \
      float og = rcp1p(-g3[r]);                                                \
      c[r] = fmaf(fg, c[r], ig * gt);                                          \
      float th = fmaf(-2.0f, rcp1p(TWOLOG2E * c[r]), 1.0f);                    \
      float h = og * th;                                                       \
      hbuf[NXT][(quad * 4 + r) * 136 + jh] = (_Float16)h;                      \
      if ((STORE_HS) && (tv) == TT - 1)                                        \
        hs[(b0 + quad * 4 + r) * HH + jh] = h;                                 \
    }                                                                          \
  }

// ---- producer helper step: h1c store of h(t-1), xacc(t+1) -> xbuf, staging --
#define PHELP_STEP(CUR, NXT, tv)                                               \
  {                                                                            \
    float2 xnew = *(const float2*)xp;                                          \
    if ((tv) < TT - 4) xp += FF;                                               \
    if ((tv) > 0) {                                                            \
      uint2 hv = *(const uint2*)&hbuf[CUR][hr_row * 136 + hr_col];             \
      *(uint2*)hcs = hv;                                                       \
      hcs += (long)BB * HH;                                                    \
    }                                                                          \
    v8s xh[2], xl[2];                                                          \
    _Pragma("unroll") for (int q = 0; q < 2; ++q) {                            \
      xh[q] = *(const v8s*)&pool[NXT][0][lane16 * 72 + q * 32 + quad * 8];     \
      xl[q] = *(const v8s*)&pool[NXT][1][lane16 * 72 + q * 32 + quad * 8];     \
    }                                                                          \
    _Pragma("unroll") for (int g = 0; g < 4; ++g) {                            \
      v4f a = {bias[g], bias[g], bias[g], bias[g]};                            \
      a = __builtin_amdgcn_mfma_f32_16x16x32_bf16(xh[0], bxh[g][0], a, 0, 0, 0);\
      a = __builtin_amdgcn_mfma_f32_16x16x32_bf16(xh[0], bxl[g][0], a, 0, 0, 0);\
      a = __builtin_amdgcn_mfma_f32_16x16x32_bf16(xl[0], bxh[g][0], a, 0, 0, 0);\
      a = __builtin_amdgcn_mfma_f32_16x16x32_bf16(xh[1], bxh[g][1], a, 0, 0, 0);\
      a = __builtin_amdgcn_mfma_f32_16x16x32_bf16(xh[1], bxl[g][1], a, 0, 0, 0);\
      a = __builtin_amdgcn_mfma_f32_16x16x32_bf16(xl[1], bxh[g][1], a, 0, 0, 0);\
      *(v4f*)&xbuf[NXT][(g * 128 + jh) * 20 + quad * 4] = a;                   \
    }                                                                          \
    {                                                                          \
      unsigned hi_, lo_;                                                       \
      split2(xreg.x, xreg.y, hi_, lo_);                                        \
      *(unsigned*)&pool[CUR][0][xr_row * 72 + xr_col] = hi_;                   \
      *(unsigned*)&pool[CUR][1][xr_row * 72 + xr_col] = lo_;                   \
    }                                                                          \
    xreg = xnew;                                                               \
  }

// ---- consumer helper step: a1acc(t+1) -> xbuf, h1 staging ------------------
#define CHELP_STEP(CUR, NXT, tv)                                               \
  {                                                                            \
    v8h a1[4];                                                                 \
    _Pragma("unroll") for (int q = 0; q < 4; ++q)                              \
        a1[q] = *(const v8h*)&sb[(NXT) * 2176 + lane16 * 136 + q * 32 + quad * 8];\
    _Pragma("unroll") for (int g = 0; g < 4; ++g) {                            \
      v4f a = {bias[g], bias[g], bias[g], bias[g]};                            \
      _Pragma("unroll") for (int q = 0; q < 4; ++q)                            \
          a = __builtin_amdgcn_mfma_f32_16x16x32_f16(a1[q], bi[g][q], a, 0, 0, 0);\
      *(v4f*)&xbuf[NXT][(g * 128 + jh) * 20 + quad * 4] = a;                   \
    }                                                                          \
    *(uint2*)&sb[(CUR) * 2176 + hr_row * 136 + hr_col] = hreg;                 \
    hreg = *(const uint2*)hp;                                                  \
    if ((tv) < TT - 4) hp += (long)BB * HH;                                    \
  }

__global__ __launch_bounds__(1024, 1) void fused_lstm_kernel(
    const float* __restrict__ x,
    const float* __restrict__ Wih0, const float* __restrict__ Whh0,
    const float* __restrict__ bih0, const float* __restrict__ bhh0,
    const float* __restrict__ Wih1, const float* __restrict__ Whh1,
    const float* __restrict__ bih1, const float* __restrict__ bhh1,
    _Float16* __restrict__ h1c, float* __restrict__ hs, int* __restrict__ flags)
{
    const int tid = threadIdx.x;
    const bool isrec = tid < 512;       // waves 0-7: recurrence
    const int l = tid & 63;
    const int lane16 = l & 15;
    const int quad = l >> 4;
    const int jh = 16 * ((tid >> 6) & 7) + lane16;
    const int stid = tid & 511;         // role-local thread id
    const int hr_row = stid >> 5;       // coop-store / staging row 0..15
    const int hr_col = (stid & 31) * 4; // 0..124 (x4 halves)

    __shared__ __align__(16) _Float16 hbuf[2][16 * 136];     //  8704 B
    __shared__ __align__(16) short    pool[2][2][16 * 72];   //  9216 B
    __shared__ __align__(16) float    xbuf[2][512 * 20];     // 81920 B

    if (blockIdx.x < 64) {
        // ================= LAYER 0 (producer) =================
        const int tile = blockIdx.x;
        const long b0 = (long)tile * 16;
        int* flagp = &flags[tile];

        if (isrec) {
            // ---- recurrence waves: only Whh0 frags + gates ----
            v8h bh[4][4];
#pragma unroll
            for (int g = 0; g < 4; ++g) {
                const int col = g * 128 + jh;
                const float sg = (g == 2) ? TWOLOG2E : LOG2E;
#pragma unroll
                for (int q = 0; q < 4; ++q) {
                    const float* p = &Whh0[(long)col * HH + q * 32 + quad * 8];
                    float4 u0 = *(const float4*)p;
                    float4 u1 = *(const float4*)(p + 4);
                    v8h t;
                    t[0]=(_Float16)(u0.x*sg); t[1]=(_Float16)(u0.y*sg);
                    t[2]=(_Float16)(u0.z*sg); t[3]=(_Float16)(u0.w*sg);
                    t[4]=(_Float16)(u1.x*sg); t[5]=(_Float16)(u1.y*sg);
                    t[6]=(_Float16)(u1.z*sg); t[7]=(_Float16)(u1.w*sg);
                    bh[g][q] = t;
                }
            }
            for (int i = tid; i < 16 * 136; i += 512) hbuf[0][i] = (_Float16)0.0f;
            float c[4] = {0.f, 0.f, 0.f, 0.f};
            __syncthreads();        // pairs: helper staged pool[0]
            light_barrier();        // pairs: helper wrote xbuf[0], pool[1]

            for (int tp = 0; tp < TT / 2; ++tp) {
                REC_STEP(0, 1, 2 * tp, 0);
                light_barrier();
                REC_STEP(1, 0, 2 * tp + 1, 0);
                light_barrier();
                if ((tp & 3) == 3 && tid == 0)
                    __hip_atomic_store(flagp, 2 * tp + 1, __ATOMIC_RELEASE,
                                       __HIP_MEMORY_SCOPE_AGENT);
            }
            light_barrier();        // pairs: helper stored h(TT-1), drained
            if (tid == 0)
                __hip_atomic_store(flagp, TT, __ATOMIC_RELEASE,
                                   __HIP_MEMORY_SCOPE_AGENT);
        } else {
            // ---- helper waves: Wih0 split-bf16 frags, staging, h1c store ----
            float bias[4];
            v8s bxh[4][2], bxl[4][2];
#pragma unroll
            for (int g = 0; g < 4; ++g) {
                const int col = g * 128 + jh;
                const float sg = (g == 2) ? TWOLOG2E : LOG2E;
                bias[g] = (bih0[col] + bhh0[col]) * sg;
#pragma unroll
                for (int q = 0; q < 2; ++q) {
                    const float* p = &Wih0[(long)col * FF + q * 32 + quad * 8];
                    float4 u0 = *(const float4*)p;
                    float4 u1 = *(const float4*)(p + 4);
                    float vv[8] = {u0.x,u0.y,u0.z,u0.w,u1.x,u1.y,u1.z,u1.w};
                    v8s hi, lo;
#pragma unroll
                    for (int e = 0; e < 8; ++e) {
                        float vs = vv[e] * sg;
                        short hbits = bf16r(vs);
                        hi[e] = hbits;
                        lo[e] = bf16r(vs - bf16tof(hbits));
                    }
                    bxh[g][q] = hi; bxl[g][q] = lo;
                }
            }
            const int xr_row = stid >> 5;
            const int xr_col = (stid & 31) * 2;
            const float* xp = &x[(b0 + xr_row) * TT * FF + xr_col];
            float2 x0v  = *(const float2*)xp;
            float2 x1v  = *(const float2*)(xp + FF);
            float2 xreg = *(const float2*)(xp + 2 * FF);
            xp += 3 * FF;
            {
                unsigned hi, lo; split2(x0v.x, x0v.y, hi, lo);
                *(unsigned*)&pool[0][0][xr_row * 72 + xr_col] = hi;
                *(unsigned*)&pool[0][1][xr_row * 72 + xr_col] = lo;
            }
            __syncthreads();
            // xacc(0) = bias + Wih0*x(0) -> xbuf[0]
            {
                v8s xh[2], xl[2];
#pragma unroll
                for (int q = 0; q < 2; ++q) {
                    xh[q] = *(const v8s*)&pool[0][0][lane16 * 72 + q * 32 + quad * 8];
                    xl[q] = *(const v8s*)&pool[0][1][lane16 * 72 + q * 32 + quad * 8];
                }
#pragma unroll
                for (int g = 0; g < 4; ++g) {
                    v4f a = {bias[g], bias[g], bias[g], bias[g]};
                    a = __builtin_amdgcn_mfma_f32_16x16x32_bf16(xh[0], bxh[g][0], a, 0, 0, 0);
                    a = __builtin_amdgcn_mfma_f32_16x16x32_bf16(xh[0], bxl[g][0], a, 0, 0, 0);
                    a = __builtin_amdgcn_mfma_f32_16x16x32_bf16(xl[0], bxh[g][0], a, 0, 0, 0);
                    a = __builtin_amdgcn_mfma_f32_16x16x32_bf16(xh[1], bxh[g][1], a, 0, 0, 0);
                    a = __builtin_amdgcn_mfma_f32_16x16x32_bf16(xh[1], bxl[g][1], a, 0, 0, 0);
                    a = __builtin_amdgcn_mfma_f32_16x16x32_bf16(xl[1], bxh[g][1], a, 0, 0, 0);
                    *(v4f*)&xbuf[0][(g * 128 + jh) * 20 + quad * 4] = a;
                }
            }
            {
                unsigned hi, lo; split2(x1v.x, x1v.y, hi, lo);
                *(unsigned*)&pool[1][0][xr_row * 72 + xr_col] = hi;
                *(unsigned*)&pool[1][1][xr_row * 72 + xr_col] = lo;
            }
            light_barrier();

            _Float16* hcs = h1c + (b0 + hr_row) * HH + hr_col;
            for (int tp = 0; tp < TT / 2; ++tp) {
                PHELP_STEP(0, 1, 2 * tp);
                light_barrier();
                PHELP_STEP(1, 0, 2 * tp + 1);
                if ((tp & 3) == 3) heavy_barrier();   // drain h1c stores
                else               light_barrier();
            }
            // epilogue: store h(TT-1) (in hbuf[0]); publish by rec tid0 after
            {
                uint2 hv = *(const uint2*)&hbuf[0][hr_row * 136 + hr_col];
                *(uint2*)hcs = hv;
            }
            heavy_barrier();
        }
    } else {
        // ================= LAYER 1 (consumer) =================
        const int tile = blockIdx.x - 64;
        const long b0 = (long)tile * 16;
        int* flagp = &flags[tile];
        _Float16* sb = (_Float16*)&pool[0][0][0];   // 2 slots, stride 2176 halves

        if (isrec) {
            v8h bh[4][4];
#pragma unroll
            for (int g = 0; g < 4; ++g) {
                const int col = g * 128 + jh;
                const float sg = (g == 2) ? TWOLOG2E : LOG2E;
#pragma unroll
                for (int q = 0; q < 4; ++q) {
                    const float* ph = &Whh1[(long)col * HH + q * 32 + quad * 8];
                    float4 v0 = *(const float4*)ph;
                    float4 v1 = *(const float4*)(ph + 4);
                    v8h s;
                    s[0]=(_Float16)(v0.x*sg); s[1]=(_Float16)(v0.y*sg);
                    s[2]=(_Float16)(v0.z*sg); s[3]=(_Float16)(v0.w*sg);
                    s[4]=(_Float16)(v1.x*sg); s[5]=(_Float16)(v1.y*sg);
                    s[6]=(_Float16)(v1.z*sg); s[7]=(_Float16)(v1.w*sg);
                    bh[g][q] = s;
                }
            }
            for (int i = tid; i < 16 * 136; i += 512) hbuf[0][i] = (_Float16)0.0f;
            float c[4] = {0.f, 0.f, 0.f, 0.f};
            if (tid == 0) wait_flag_ge(flagp, 15);
            __syncthreads();        // releases helper global reads
            light_barrier();        // helper staged sb[0]
            light_barrier();        // helper wrote xbuf[0], sb[1]

            for (int tp = 0; tp < TT / 2; ++tp) {
                if ((tp & 3) == 0 && tp > 0) {
                    if (tid == 0)
                        wait_flag_ge(flagp, (2 * tp + 15 < TT) ? 2 * tp + 15 : TT);
                    light_barrier();
                }
                REC_STEP(0, 1, 2 * tp, 1);
                light_barrier();
                REC_STEP(1, 0, 2 * tp + 1, 1);
                light_barrier();
            }
        } else {
            float bias[4];
            v8h bi[4][4];
#pragma unroll
            for (int g = 0; g < 4; ++g) {
                const int col = g * 128 + jh;
                const float sg = (g == 2) ? TWOLOG2E : LOG2E;
                bias[g] = (bih1[col] + bhh1[col]) * sg;
#pragma unroll
                for (int q = 0; q < 4; ++q) {
                    const float* pi = &Wih1[(long)col * HH + q * 32 + quad * 8];
                    float4 u0 = *(const float4*)pi;
                    float4 u1 = *(const float4*)(pi + 4);
                    v8h t;
                    t[0]=(_Float16)(u0.x*sg); t[1]=(_Float16)(u0.y*sg);
                    t[2]=(_Float16)(u0.z*sg); t[3]=(_Float16)(u0.w*sg);
                    t[4]=(_Float16)(u1.x*sg); t[5]=(_Float16)(u1.y*sg);
                    t[6]=(_Float16)(u1.z*sg); t[7]=(_Float16)(u1.w*sg);
                    bi[g][q] = t;
                }
            }
            __syncthreads();        // after rec tid0's flag wait

            const _Float16* hp = h1c + (b0 + hr_row) * HH + hr_col;  // t=0
            uint2 h0v  = *(const uint2*)hp;
            uint2 h1v  = *(const uint2*)(hp + (long)BB * HH);
            uint2 hreg = *(const uint2*)(hp + 2L * BB * HH);
            hp += 3L * BB * HH;
            *(uint2*)&sb[0 * 2176 + hr_row * 136 + hr_col] = h0v;
            light_barrier();
            // a1acc(0) = bias + Wih1*h1(0) -> xbuf[0]
            {
                v8h a1[4];
#pragma unroll
                for (int q = 0; q < 4; ++q)
                    a1[q] = *(const v8h*)&sb[0 * 2176 + lane16 * 136 + q * 32 + quad * 8];
#pragma unroll
                for (int g = 0; g < 4; ++g) {
                    v4f a = {bias[g], bias[g], bias[g], bias[g]};
#pragma unroll
                    for (int q = 0; q < 4; ++q)
                        a = __builtin_amdgcn_mfma_f32_16x16x32_f16(a1[q], bi[g][q], a, 0, 0, 0);
                    *(v4f*)&xbuf[0][(g * 128 + jh) * 20 + quad * 4] = a;
                }
            }
            *(uint2*)&sb[1 * 2176 + hr_row * 136 + hr_col] = h1v;
            light_barrier();

            for (int tp = 0; tp < TT / 2; ++tp) {
                if ((tp & 3) == 0 && tp > 0) light_barrier();
                CHELP_STEP(0, 1, 2 * tp);
                light_barrier();
                CHELP_STEP(1, 0, 2 * tp + 1);
                light_barrier();
            }
        }
    }
}

// ---------------- FC head: out = relu(h @ fc1^T + b1) @ fc2^T + b2 ----------
__global__ __launch_bounds__(64) void head_kernel(
    const float* __restrict__ h, const float* __restrict__ w1,
    const float* __restrict__ b1, const float* __restrict__ w2,
    const float* __restrict__ b2, float* __restrict__ out)
{
    const int b = blockIdx.x;
    const int n = threadIdx.x;
    float acc = b1[n];
#pragma unroll
    for (int k = 0; k < HH; ++k)
        acc = fmaf(w1[n * HH + k], h[b * HH + k], acc);
    float v = fmaxf(acc, 0.0f) * w2[n];
#pragma unroll
    for (int off = 32; off > 0; off >>= 1)
        v += __shfl_down(v, off);
    if (n == 0) out[b] = v + b2[0];
}

extern "C" void kernel_launch(void* const* d_in, const int* in_sizes, int n_in,
                              void* d_out, int out_size, void* d_ws, size_t ws_size,
                              hipStream_t stream)
{
    const float* x    = (const float*)d_in[0];
    const float* Wih0 = (const float*)d_in[1];
    const float* Whh0 = (const float*)d_in[2];
    const float* bih0 = (const float*)d_in[3];
    const float* bhh0 = (const float*)d_in[4];
    const float* Wih1 = (const float*)d_in[5];
    const float* Whh1 = (const float*)d_in[6];
    const float* bih1 = (const float*)d_in[7];
    const float* bhh1 = (const float*)d_in[8];
    const float* w1   = (const float*)d_in[9];
    const float* b1   = (const float*)d_in[10];
    const float* w2   = (const float*)d_in[11];
    const float* b2   = (const float*)d_in[12];
    float* out = (float*)d_out;

    char* ws = (char*)d_ws;
    _Float16* h1c = (_Float16*)ws;                              // 134 MB, [t][B][H]
    float* hs  = (float*)(ws + (size_t)BB * TT * HH * sizeof(_Float16));
    int* flags = (int*)(ws + (size_t)BB * TT * HH * sizeof(_Float16)
                           + (size_t)BB * HH * sizeof(float));

    hipMemsetAsync(flags, 0, 64 * sizeof(int), stream);

    fused_lstm_kernel<<<128, 1024, 0, stream>>>(
        x, Wih0, Whh0, bih0, bhh0, Wih1, Whh1, bih1, bhh1, h1c, hs, flags);
    head_kernel<<<BB, 64, 0, stream>>>(hs, w1, b1, w2, b2, out);
}